// Round 3
// baseline (340.665 us; speedup 1.0000x reference)
//
#include <hip/hip_runtime.h>
#include <hip/hip_bf16.h>

#define B_ 2048
#define N_ 8
#define D_ 1024
#define V_ 4096
#define LN_EPS_ 1e-5f

typedef __bf16 bf16x8 __attribute__((ext_vector_type(8)));
typedef float f32x4 __attribute__((ext_vector_type(4)));

#define GLB(p) ((const __attribute__((address_space(1))) void*)(p))
#define LDSP(p) ((__attribute__((address_space(3))) void*)(p))

static __device__ __forceinline__ unsigned short f2bf(float x) {
    union { float f; unsigned int u; } v;
    v.f = x;
    unsigned int r = v.u + 0x7fffu + ((v.u >> 16) & 1u);
    return (unsigned short)(r >> 16);
}

// ---------------------------------------------------------------------------
// prep: fused  (a) W_pred (N,D,V) f32 -> Wt (N,V,D) bf16   [blocks 2048..10239]
//              (b) gather+cumsum+LN+GELU -> H (N,B,D) bf16 [blocks 0..2047]
// ---------------------------------------------------------------------------
__global__ __launch_bounds__(256) void prep(const float* __restrict__ ie,
                                            const int* __restrict__ feats,
                                            const float* __restrict__ emb,
                                            const float* __restrict__ gamma,
                                            const float* __restrict__ beta,
                                            const float* __restrict__ W,
                                            unsigned short* __restrict__ H,
                                            unsigned short* __restrict__ Wt) {
    const int bid = blockIdx.x;
    const int t = threadIdx.x;

    if (bid >= 2048) {
        // ---- wconv tile ----
        __shared__ unsigned short tile[64][65];
        const int w  = bid - 2048;
        const int v0 = (w & 63) * 64;
        const int d0 = ((w >> 6) & 15) * 64;
        const int n  = w >> 10;
        const int tx = t & 15, ty = t >> 4;
#pragma unroll
        for (int i = 0; i < 4; ++i) {
            const int d = ty + i * 16;
            const float4 w4 = *(const float4*)&W[((size_t)n * D_ + d0 + d) * V_ + v0 + tx * 4];
            tile[d][tx * 4 + 0] = f2bf(w4.x);
            tile[d][tx * 4 + 1] = f2bf(w4.y);
            tile[d][tx * 4 + 2] = f2bf(w4.z);
            tile[d][tx * 4 + 3] = f2bf(w4.w);
        }
        __syncthreads();
#pragma unroll
        for (int i = 0; i < 4; ++i) {
            const int v = ty + i * 16;
            ushort4 pk;
            pk.x = tile[tx * 4 + 0][v];
            pk.y = tile[tx * 4 + 1][v];
            pk.z = tile[tx * 4 + 2][v];
            pk.w = tile[tx * 4 + 3][v];
            *reinterpret_cast<ushort4*>(&Wt[((size_t)n * V_ + v0 + v) * D_ + d0 + tx * 4]) = pk;
        }
    } else {
        // ---- stage1: one block per b ----
        __shared__ float redS[4], redQ[4];
        const int b = bid;
        const int d0 = t * 4;
        const int lane = t & 63, wid = t >> 6;

        float4 s  = *(const float4*)&ie[(size_t)b * D_ + d0];
        const float4 g4 = *(const float4*)&gamma[d0];
        const float4 be4 = *(const float4*)&beta[d0];

        int fc[N_];
#pragma unroll
        for (int n = 0; n < N_; ++n) fc[n] = feats[b * N_ + n];

#pragma unroll
        for (int n = 0; n < N_; ++n) {
            float ls = s.x + s.y + s.z + s.w;
            float lq = s.x * s.x + s.y * s.y + s.z * s.z + s.w * s.w;
#pragma unroll
            for (int off = 32; off > 0; off >>= 1) {
                ls += __shfl_down(ls, off, 64);
                lq += __shfl_down(lq, off, 64);
            }
            if (lane == 0) { redS[wid] = ls; redQ[wid] = lq; }
            __syncthreads();
            const float tot  = redS[0] + redS[1] + redS[2] + redS[3];
            const float totq = redQ[0] + redQ[1] + redQ[2] + redQ[3];
            __syncthreads();

            const float mu   = tot * (1.0f / D_);
            const float var  = totq * (1.0f / D_) - mu * mu;
            const float rstd = rsqrtf(var + LN_EPS_);

            float h0 = (s.x - mu) * rstd * g4.x + be4.x;
            float h1 = (s.y - mu) * rstd * g4.y + be4.y;
            float h2 = (s.z - mu) * rstd * g4.z + be4.z;
            float h3 = (s.w - mu) * rstd * g4.w + be4.w;
            h0 = 0.5f * h0 * (1.0f + erff(h0 * 0.70710678f));
            h1 = 0.5f * h1 * (1.0f + erff(h1 * 0.70710678f));
            h2 = 0.5f * h2 * (1.0f + erff(h2 * 0.70710678f));
            h3 = 0.5f * h3 * (1.0f + erff(h3 * 0.70710678f));

            ushort4 pk;
            pk.x = f2bf(h0); pk.y = f2bf(h1); pk.z = f2bf(h2); pk.w = f2bf(h3);
            *reinterpret_cast<ushort4*>(&H[((size_t)n * B_ + b) * D_ + d0]) = pk;

            const float4 e = *(const float4*)&emb[((size_t)n * V_ + fc[n]) * (size_t)D_ + d0];
            s.x += e.x; s.y += e.y; s.z += e.z; s.w += e.w;
        }
    }
}

// ---------------------------------------------------------------------------
// gemm8: 256x256xBK64, 8 waves, 4-phase/K-tile, PERSISTENT over 4 vt-tiles.
// One block per CU (grid=256). 64 continuous K-tiles; tile15 of vt-iter i
// stages tile0 of vt-iter i+1 (no mid-kernel drain). Epilogue stores inject
// into the vmcnt stream (conservative over-wait only). Bias hoisted.
// Swizzle: physical 16B slot = logical ^ (row&7), inverse applied on global src.
// ---------------------------------------------------------------------------
#define MF(a, b, c) __builtin_amdgcn_mfma_f32_16x16x32_bf16((a), (b), (c), 0, 0, 0)

#define STG_A(u, APTR, bb) __builtin_amdgcn_global_load_lds( \
    GLB((APTR) + (size_t)((u) * 64 + srow) * D_ + gsl), \
    LDSP(lds + (bb) + (u) * 8192 + t * 16), 16, 0, 0)
#define STG_B(u, BPTR, bb) __builtin_amdgcn_global_load_lds( \
    GLB((BPTR) + (size_t)((u) * 64 + srow) * D_ + gsl), \
    LDSP(lds + (bb) + 32768 + (u) * 8192 + t * 16), 16, 0, 0)

#define RD_A(i, ks, bb) (*(const bf16x8*)(lds + (bb) + ((i) >> 1) * 8192 + \
    (((i) & 1) * 32 + wr * 16 + lrow) * 128 + ((((ks) * 4 + lkq) ^ sw) * 16)))
#define RD_B(j, ks, bb) (*(const bf16x8*)(lds + (bb) + 32768 + wc * 8192 + \
    ((j) * 16 + lrow) * 128 + ((((ks) * 4 + lkq) ^ sw) * 16)))

#define QUADP(i0, i1) \
    _Pragma("unroll") for (int j = 0; j < 4; ++j) { \
        acc[i0][j] = MF(A00, Bf[j][0], acc[i0][j]); \
        acc[i0][j] = MF(A01, Bf[j][1], acc[i0][j]); \
        acc[i1][j] = MF(A10, Bf[j][0], acc[i1][j]); \
        acc[i1][j] = MF(A11, Bf[j][1], acc[i1][j]); \
    }

#define TILE(bc, bn, ANXT, BNXT) { \
    bf16x8 Bf[4][2]; \
    asm volatile("s_waitcnt vmcnt(3)" ::: "memory"); \
    __builtin_amdgcn_s_barrier(); \
    _Pragma("unroll") for (int j = 0; j < 4; ++j) { Bf[j][0] = RD_B(j, 0, bc); Bf[j][1] = RD_B(j, 1, bc); } \
    { bf16x8 A00 = RD_A(0, 0, bc), A01 = RD_A(0, 1, bc), A10 = RD_A(1, 0, bc), A11 = RD_A(1, 1, bc); \
      STG_B(0, BNXT, bn); STG_B(1, BNXT, bn); \
      __builtin_amdgcn_s_setprio(1); QUADP(0, 1); __builtin_amdgcn_s_setprio(0); } \
    asm volatile("s_waitcnt vmcnt(4)" ::: "memory"); \
    __builtin_amdgcn_s_barrier(); \
    { bf16x8 A00 = RD_A(2, 0, bc), A01 = RD_A(2, 1, bc), A10 = RD_A(3, 0, bc), A11 = RD_A(3, 1, bc); \
      STG_B(2, BNXT, bn); STG_B(3, BNXT, bn); \
      __builtin_amdgcn_s_setprio(1); QUADP(2, 3); __builtin_amdgcn_s_setprio(0); } \
    asm volatile("s_waitcnt vmcnt(4)" ::: "memory"); \
    __builtin_amdgcn_s_barrier(); \
    { bf16x8 A00 = RD_A(4, 0, bc), A01 = RD_A(4, 1, bc), A10 = RD_A(5, 0, bc), A11 = RD_A(5, 1, bc); \
      STG_A(0, ANXT, bn); STG_A(1, ANXT, bn); \
      __builtin_amdgcn_s_setprio(1); QUADP(4, 5); __builtin_amdgcn_s_setprio(0); } \
    asm volatile("s_waitcnt vmcnt(6)" ::: "memory"); \
    __builtin_amdgcn_s_barrier(); \
    { bf16x8 A00 = RD_A(6, 0, bc), A01 = RD_A(6, 1, bc), A10 = RD_A(7, 0, bc), A11 = RD_A(7, 1, bc); \
      STG_A(2, ANXT, bn); STG_A(3, ANXT, bn); \
      __builtin_amdgcn_s_setprio(1); QUADP(6, 7); __builtin_amdgcn_s_setprio(0); } \
}

#define TILE_LAST(bc) { \
    bf16x8 Bf[4][2]; \
    asm volatile("s_waitcnt vmcnt(3)" ::: "memory"); \
    __builtin_amdgcn_s_barrier(); \
    _Pragma("unroll") for (int j = 0; j < 4; ++j) { Bf[j][0] = RD_B(j, 0, bc); Bf[j][1] = RD_B(j, 1, bc); } \
    { bf16x8 A00 = RD_A(0, 0, bc), A01 = RD_A(0, 1, bc), A10 = RD_A(1, 0, bc), A11 = RD_A(1, 1, bc); \
      __builtin_amdgcn_s_setprio(1); QUADP(0, 1); __builtin_amdgcn_s_setprio(0); } \
    asm volatile("s_waitcnt vmcnt(2)" ::: "memory"); \
    __builtin_amdgcn_s_barrier(); \
    { bf16x8 A00 = RD_A(2, 0, bc), A01 = RD_A(2, 1, bc), A10 = RD_A(3, 0, bc), A11 = RD_A(3, 1, bc); \
      __builtin_amdgcn_s_setprio(1); QUADP(2, 3); __builtin_amdgcn_s_setprio(0); } \
    asm volatile("s_waitcnt vmcnt(1)" ::: "memory"); \
    __builtin_amdgcn_s_barrier(); \
    { bf16x8 A00 = RD_A(4, 0, bc), A01 = RD_A(4, 1, bc), A10 = RD_A(5, 0, bc), A11 = RD_A(5, 1, bc); \
      __builtin_amdgcn_s_setprio(1); QUADP(4, 5); __builtin_amdgcn_s_setprio(0); } \
    asm volatile("s_waitcnt vmcnt(0)" ::: "memory"); \
    __builtin_amdgcn_s_barrier(); \
    { bf16x8 A00 = RD_A(6, 0, bc), A01 = RD_A(6, 1, bc), A10 = RD_A(7, 0, bc), A11 = RD_A(7, 1, bc); \
      __builtin_amdgcn_s_setprio(1); QUADP(6, 7); __builtin_amdgcn_s_setprio(0); } \
}

__global__ __launch_bounds__(512, 2) void gemm8(const unsigned short* __restrict__ H,
                                                const unsigned short* __restrict__ Wt,
                                                const float* __restrict__ bp,
                                                float* __restrict__ out) {
    extern __shared__ char lds[];
    const int bid = blockIdx.x;
    // bijective XCD chunking: XCD k (= bid%8) owns swz range [32k, 32k+32) = one n
    const int swz = (bid & 7) * 32 + (bid >> 3);
    const int n   = swz >> 5;
    const int mt  = (swz >> 2) & 7;
    const int vtg = swz & 3;

    const int t = threadIdx.x;
    const int wid = t >> 6, lane = t & 63;
    const int wr = wid >> 2, wc = wid & 3;

    const unsigned short* Ab = H  + ((size_t)n * B_ + (size_t)mt * 256) * D_;
    const unsigned short* Bb = Wt + ((size_t)n * V_ + (size_t)vtg * 1024) * D_;

    const int srow = t >> 3;
    const int gsl  = ((t & 7) ^ (srow & 7)) * 8;
    const int lrow = lane & 15;
    const int lkq  = lane >> 4;
    const int sw   = lane & 7;
    const int col  = lane & 15;
    const int rg   = (lane >> 4) * 4;

    // hoist bias for all 4 vt-iters (oldest VMEM ops -> retire before pipeline counts matter)
    f32x4 bias0, bias1, bias2, bias3;
#pragma unroll
    for (int j = 0; j < 4; ++j) {
        const size_t bo = (size_t)n * V_ + (size_t)vtg * 1024 + wc * 64 + j * 16 + col;
        bias0[j] = bp[bo];
        bias1[j] = bp[bo + 256];
        bias2[j] = bp[bo + 512];
        bias3[j] = bp[bo + 768];
    }
    __builtin_amdgcn_sched_barrier(0);

    f32x4 acc[8][4] = {};

    // prologue: stage tile 0 into buf0 (B0 B1 B2 B3 A0 A1 A2 A3)
    STG_B(0, Bb, 0); STG_B(1, Bb, 0); STG_B(2, Bb, 0); STG_B(3, Bb, 0);
    STG_A(0, Ab, 0); STG_A(1, Ab, 0); STG_A(2, Ab, 0); STG_A(3, Ab, 0);

    const unsigned short* Bc = Bb;
#pragma unroll 1
    for (int it = 0; it < 4; ++it) {
        const unsigned short* Bn = Bc + (size_t)256 * D_;  // next vt's B panel
#pragma unroll 1
        for (int lt2 = 0; lt2 < 7; ++lt2) {   // tiles 0..13 of this vt
            const int k0 = lt2 * 128;
            TILE(0, 65536, Ab + k0 + 64, Bc + k0 + 64);
            TILE(65536, 0, Ab + k0 + 128, Bc + k0 + 128);
        }
        TILE(0, 65536, Ab + 960, Bc + 960);   // tile 14 (stages tile 15)
        if (it < 3) { TILE(65536, 0, Ab, Bn); }   // tile 15 stages NEXT vt tile 0
        else        { TILE_LAST(65536); }         // final drain

        // epilogue for vt = vtg*4 + it (stores inject into vmcnt stream: safe over-wait)
        const int gc0 = (vtg * 4 + it) * 256 + wc * 64 + col;
        const f32x4 bs = (it == 0) ? bias0 : (it == 1) ? bias1 : (it == 2) ? bias2 : bias3;
#pragma unroll
        for (int i = 0; i < 8; ++i) {
            const int row = mt * 256 + i * 32 + wr * 16 + rg;
#pragma unroll
            for (int j = 0; j < 4; ++j) {
                const int gcol = gc0 + j * 16;
#pragma unroll
                for (int r = 0; r < 4; ++r)
                    out[((size_t)(row + r) * N_ + n) * V_ + gcol] = acc[i][j][r] + bs[j];
            }
        }
        if (it < 3) {
#pragma unroll
            for (int i = 0; i < 8; ++i)
#pragma unroll
                for (int j = 0; j < 4; ++j)
                    acc[i][j] = (f32x4){0.f, 0.f, 0.f, 0.f};
        }
        Bc = Bn;
    }
}

// ---------------------------------------------------------------------------
extern "C" void kernel_launch(void* const* d_in, const int* in_sizes, int n_in,
                              void* d_out, int out_size, void* d_ws, size_t ws_size,
                              hipStream_t stream) {
    const float* ie  = (const float*)d_in[0];
    const int*   fts = (const int*)d_in[1];
    const float* emb = (const float*)d_in[2];
    const float* W   = (const float*)d_in[3];
    const float* bp  = (const float*)d_in[4];
    const float* gam = (const float*)d_in[5];
    const float* bet = (const float*)d_in[6];
    float* out = (float*)d_out;

    unsigned short* Wt = (unsigned short*)d_ws;                                     // 64 MiB
    unsigned short* H  = (unsigned short*)((char*)d_ws + (size_t)N_ * V_ * D_ * 2); // +32 MiB

    (void)hipFuncSetAttribute(reinterpret_cast<const void*>(gemm8),
                              hipFuncAttributeMaxDynamicSharedMemorySize, 131072);

    prep<<<dim3(2048 + 8192), dim3(256), 0, stream>>>(ie, fts, emb, gam, bet, W, H, Wt);
    gemm8<<<dim3(256), dim3(512), 131072, stream>>>(H, Wt, bp, out);
}

// Round 4
// 244.434 us; speedup vs baseline: 1.3937x; 1.3937x over previous
//
#include <hip/hip_runtime.h>
#include <hip/hip_bf16.h>

#define B_ 2048
#define N_ 8
#define D_ 1024
#define V_ 4096
#define LN_EPS_ 1e-5f

typedef __bf16 bf16x8 __attribute__((ext_vector_type(8)));
typedef float f32x4 __attribute__((ext_vector_type(4)));

#define GLB(p) ((const __attribute__((address_space(1))) void*)(p))
#define LDSP(p) ((__attribute__((address_space(3))) void*)(p))

static __device__ __forceinline__ unsigned short f2bf(float x) {
    union { float f; unsigned int u; } v;
    v.f = x;
    unsigned int r = v.u + 0x7fffu + ((v.u >> 16) & 1u);
    return (unsigned short)(r >> 16);
}

// ---------------------------------------------------------------------------
// prep: fused  (a) W_pred (N,D,V) f32 -> Wt (N,V,D) bf16   [blocks 2048..10239]
//              (b) gather+cumsum+LN+GELU -> H (N,B,D) bf16 [blocks 0..2047]
// ---------------------------------------------------------------------------
__global__ __launch_bounds__(256) void prep(const float* __restrict__ ie,
                                            const int* __restrict__ feats,
                                            const float* __restrict__ emb,
                                            const float* __restrict__ gamma,
                                            const float* __restrict__ beta,
                                            const float* __restrict__ W,
                                            unsigned short* __restrict__ H,
                                            unsigned short* __restrict__ Wt) {
    const int bid = blockIdx.x;
    const int t = threadIdx.x;

    if (bid >= 2048) {
        __shared__ unsigned short tile[64][65];
        const int w  = bid - 2048;
        const int v0 = (w & 63) * 64;
        const int d0 = ((w >> 6) & 15) * 64;
        const int n  = w >> 10;
        const int tx = t & 15, ty = t >> 4;
#pragma unroll
        for (int i = 0; i < 4; ++i) {
            const int d = ty + i * 16;
            const float4 w4 = *(const float4*)&W[((size_t)n * D_ + d0 + d) * V_ + v0 + tx * 4];
            tile[d][tx * 4 + 0] = f2bf(w4.x);
            tile[d][tx * 4 + 1] = f2bf(w4.y);
            tile[d][tx * 4 + 2] = f2bf(w4.z);
            tile[d][tx * 4 + 3] = f2bf(w4.w);
        }
        __syncthreads();
#pragma unroll
        for (int i = 0; i < 4; ++i) {
            const int v = ty + i * 16;
            ushort4 pk;
            pk.x = tile[tx * 4 + 0][v];
            pk.y = tile[tx * 4 + 1][v];
            pk.z = tile[tx * 4 + 2][v];
            pk.w = tile[tx * 4 + 3][v];
            *reinterpret_cast<ushort4*>(&Wt[((size_t)n * V_ + v0 + v) * D_ + d0 + tx * 4]) = pk;
        }
    } else {
        __shared__ float redS[4], redQ[4];
        const int b = bid;
        const int d0 = t * 4;
        const int lane = t & 63, wid = t >> 6;

        float4 s  = *(const float4*)&ie[(size_t)b * D_ + d0];
        const float4 g4 = *(const float4*)&gamma[d0];
        const float4 be4 = *(const float4*)&beta[d0];

        int fc[N_];
#pragma unroll
        for (int n = 0; n < N_; ++n) fc[n] = feats[b * N_ + n];

#pragma unroll
        for (int n = 0; n < N_; ++n) {
            float ls = s.x + s.y + s.z + s.w;
            float lq = s.x * s.x + s.y * s.y + s.z * s.z + s.w * s.w;
#pragma unroll
            for (int off = 32; off > 0; off >>= 1) {
                ls += __shfl_down(ls, off, 64);
                lq += __shfl_down(lq, off, 64);
            }
            if (lane == 0) { redS[wid] = ls; redQ[wid] = lq; }
            __syncthreads();
            const float tot  = redS[0] + redS[1] + redS[2] + redS[3];
            const float totq = redQ[0] + redQ[1] + redQ[2] + redQ[3];
            __syncthreads();

            const float mu   = tot * (1.0f / D_);
            const float var  = totq * (1.0f / D_) - mu * mu;
            const float rstd = rsqrtf(var + LN_EPS_);

            float h0 = (s.x - mu) * rstd * g4.x + be4.x;
            float h1 = (s.y - mu) * rstd * g4.y + be4.y;
            float h2 = (s.z - mu) * rstd * g4.z + be4.z;
            float h3 = (s.w - mu) * rstd * g4.w + be4.w;
            h0 = 0.5f * h0 * (1.0f + erff(h0 * 0.70710678f));
            h1 = 0.5f * h1 * (1.0f + erff(h1 * 0.70710678f));
            h2 = 0.5f * h2 * (1.0f + erff(h2 * 0.70710678f));
            h3 = 0.5f * h3 * (1.0f + erff(h3 * 0.70710678f));

            ushort4 pk;
            pk.x = f2bf(h0); pk.y = f2bf(h1); pk.z = f2bf(h2); pk.w = f2bf(h3);
            *reinterpret_cast<ushort4*>(&H[((size_t)n * B_ + b) * D_ + d0]) = pk;

            const float4 e = *(const float4*)&emb[((size_t)n * V_ + fc[n]) * (size_t)D_ + d0];
            s.x += e.x; s.y += e.y; s.z += e.z; s.w += e.w;
        }
    }
}

// ---------------------------------------------------------------------------
// gemm4: 256x256 tile, BK=32, 8 waves. 4 LDS buffers (A16K+B16K each = 128KB),
// 3-deep counted prefetch: per K-tile exactly ONE vmcnt(8) + ONE barrier, then
// free-running {stage next+3 | 12 ds_read_b128 | 32 independent MFMA}.
// Swizzle: phys k-slot = logical ^ (row&3); inverse applied on global source.
// ---------------------------------------------------------------------------
#define MF(a, b, c) __builtin_amdgcn_mfma_f32_16x16x32_bf16((a), (b), (c), 0, 0, 0)

#define STAGE(As, Bs, bb) { \
    __builtin_amdgcn_global_load_lds(GLB((As) + (size_t)srow * D_ + gsl),         LDSP(lds + (bb) + t * 16), 16, 0, 0); \
    __builtin_amdgcn_global_load_lds(GLB((As) + (size_t)(srow + 128) * D_ + gsl), LDSP(lds + (bb) + 8192 + t * 16), 16, 0, 0); \
    __builtin_amdgcn_global_load_lds(GLB((Bs) + (size_t)srow * D_ + gsl),         LDSP(lds + (bb) + 16384 + t * 16), 16, 0, 0); \
    __builtin_amdgcn_global_load_lds(GLB((Bs) + (size_t)(srow + 128) * D_ + gsl), LDSP(lds + (bb) + 24576 + t * 16), 16, 0, 0); \
}

#define RD_A(i, bb) (*(const bf16x8*)(lds + (bb) + ((i) * 32 + wr * 16 + lrow) * 64 + swk))
#define RD_B(j, bb) (*(const bf16x8*)(lds + (bb) + 16384 + (wc * 64 + (j) * 16 + lrow) * 64 + swk))

#define TILE1(bc, bn, As, Bs) { \
    asm volatile("s_waitcnt vmcnt(8)" ::: "memory"); \
    __builtin_amdgcn_s_barrier(); \
    STAGE(As, Bs, bn); \
    bf16x8 Bf[4], Af[4]; \
    _Pragma("unroll") for (int j = 0; j < 4; ++j) Bf[j] = RD_B(j, bc); \
    _Pragma("unroll") for (int i = 0; i < 4; ++i) Af[i] = RD_A(i, bc); \
    __builtin_amdgcn_s_setprio(1); \
    _Pragma("unroll") for (int i = 0; i < 4; ++i) \
        _Pragma("unroll") for (int j = 0; j < 4; ++j) \
            acc[i][j] = MF(Af[i], Bf[j], acc[i][j]); \
    __builtin_amdgcn_s_setprio(0); \
    _Pragma("unroll") for (int i = 0; i < 4; ++i) Af[i] = RD_A((i) + 4, bc); \
    __builtin_amdgcn_s_setprio(1); \
    _Pragma("unroll") for (int i = 0; i < 4; ++i) \
        _Pragma("unroll") for (int j = 0; j < 4; ++j) \
            acc[i + 4][j] = MF(Af[i], Bf[j], acc[i + 4][j]); \
    __builtin_amdgcn_s_setprio(0); \
}

__global__ __launch_bounds__(512, 2) void gemm4(const unsigned short* __restrict__ H,
                                                const unsigned short* __restrict__ Wt,
                                                const float* __restrict__ bp,
                                                float* __restrict__ out) {
    extern __shared__ char lds[];
    const int bid = blockIdx.x;
    // XCD chunking: XCD k (= bid%8) owns logical range [128k,128k+128) = one n
    const int logical = (bid & 7) * 128 + (bid >> 3);
    const int n  = logical >> 7;
    const int mt = (logical >> 4) & 7;
    const int vt = logical & 15;

    const int t = threadIdx.x;
    const int wid = t >> 6, lane = t & 63;
    const int wr = wid >> 2, wc = wid & 3;

    const unsigned short* Ab = H  + ((size_t)n * B_ + (size_t)mt * 256) * D_;
    const unsigned short* Bb = Wt + ((size_t)n * V_ + (size_t)vt * 256) * D_;

    const int srow = t >> 2;                       // 0..127
    const int gsl  = ((t & 3) ^ (srow & 3)) * 8;   // inverse-swizzled source k-slot
    const int lrow = lane & 15;
    const int swk  = (((lane >> 4) ^ (lrow & 3))) * 16;
    const int col  = lane & 15;
    const int rg   = (lane >> 4) * 4;

    // bias (hoisted; retires before first vmcnt(8) matters)
    float bias[4];
#pragma unroll
    for (int j = 0; j < 4; ++j)
        bias[j] = bp[(size_t)n * V_ + vt * 256 + wc * 64 + j * 16 + col];
    __builtin_amdgcn_sched_barrier(0);

    f32x4 acc[8][4] = {};

    // prologue: stage tiles 0,1,2 into bufs 0,1,2
    STAGE(Ab, Bb, 0);
    STAGE(Ab + 32, Bb + 32, 32768);
    STAGE(Ab + 64, Bb + 64, 65536);

#pragma unroll 1
    for (int it = 0; it < 8; ++it) {
        const int k0 = it * 128;
        const int s0 = k0 + 96;                          // always < 1024
        int s1 = k0 + 128; if (s1 >= 1024) s1 = 0;       // clamped dummy on last iter
        int s2 = k0 + 160; if (s2 >= 1024) s2 = 0;
        int s3 = k0 + 192; if (s3 >= 1024) s3 = 0;
        TILE1(0,     98304, Ab + s0, Bb + s0);
        TILE1(32768, 0,     Ab + s1, Bb + s1);
        TILE1(65536, 32768, Ab + s2, Bb + s2);
        TILE1(98304, 65536, Ab + s3, Bb + s3);
    }
    asm volatile("s_waitcnt vmcnt(0)" ::: "memory");

    // epilogue: C/D layout col = lane&15, row = (lane>>4)*4 + reg
    const int gc0 = vt * 256 + wc * 64 + col;
#pragma unroll
    for (int i = 0; i < 8; ++i) {
        const int row = mt * 256 + i * 32 + wr * 16 + rg;
#pragma unroll
        for (int j = 0; j < 4; ++j) {
            const int gcol = gc0 + j * 16;
#pragma unroll
            for (int r = 0; r < 4; ++r)
                out[((size_t)(row + r) * N_ + n) * V_ + gcol] = acc[i][j][r] + bias[j];
        }
    }
}

// ---------------------------------------------------------------------------
extern "C" void kernel_launch(void* const* d_in, const int* in_sizes, int n_in,
                              void* d_out, int out_size, void* d_ws, size_t ws_size,
                              hipStream_t stream) {
    const float* ie  = (const float*)d_in[0];
    const int*   fts = (const int*)d_in[1];
    const float* emb = (const float*)d_in[2];
    const float* W   = (const float*)d_in[3];
    const float* bp  = (const float*)d_in[4];
    const float* gam = (const float*)d_in[5];
    const float* bet = (const float*)d_in[6];
    float* out = (float*)d_out;

    unsigned short* Wt = (unsigned short*)d_ws;                                     // 64 MiB
    unsigned short* H  = (unsigned short*)((char*)d_ws + (size_t)N_ * V_ * D_ * 2); // +32 MiB

    (void)hipFuncSetAttribute(reinterpret_cast<const void*>(gemm4),
                              hipFuncAttributeMaxDynamicSharedMemorySize, 131072);

    prep<<<dim3(2048 + 8192), dim3(256), 0, stream>>>(ie, fts, emb, gam, bet, W, H, Wt);
    gemm4<<<dim3(1024), dim3(512), 131072, stream>>>(H, Wt, bp, out);
}

// Round 5
// 243.913 us; speedup vs baseline: 1.3967x; 1.0021x over previous
//
#include <hip/hip_runtime.h>
#include <hip/hip_bf16.h>

#define B_ 2048
#define N_ 8
#define D_ 1024
#define V_ 4096
#define LN_EPS_ 1e-5f

typedef __bf16 bf16x8 __attribute__((ext_vector_type(8)));
typedef float f32x4 __attribute__((ext_vector_type(4)));

#define GLB(p) ((const __attribute__((address_space(1))) void*)(p))
#define LDSP(p) ((__attribute__((address_space(3))) void*)(p))

static __device__ __forceinline__ unsigned short f2bf(float x) {
    union { float f; unsigned int u; } v;
    v.f = x;
    unsigned int r = v.u + 0x7fffu + ((v.u >> 16) & 1u);
    return (unsigned short)(r >> 16);
}

// ---------------------------------------------------------------------------
// prep: fused  (a) W_pred (N,D,V) f32 -> Wt (N,V,D) bf16   [blocks 2048..10239]
//              (b) gather+cumsum+LN+GELU -> H (N,B,D) bf16 [blocks 0..2047]
// ---------------------------------------------------------------------------
__global__ __launch_bounds__(256) void prep(const float* __restrict__ ie,
                                            const int* __restrict__ feats,
                                            const float* __restrict__ emb,
                                            const float* __restrict__ gamma,
                                            const float* __restrict__ beta,
                                            const float* __restrict__ W,
                                            unsigned short* __restrict__ H,
                                            unsigned short* __restrict__ Wt) {
    const int bid = blockIdx.x;
    const int t = threadIdx.x;

    if (bid >= 2048) {
        __shared__ unsigned short tile[64][65];
        const int w  = bid - 2048;
        const int v0 = (w & 63) * 64;
        const int d0 = ((w >> 6) & 15) * 64;
        const int n  = w >> 10;
        const int tx = t & 15, ty = t >> 4;
#pragma unroll
        for (int i = 0; i < 4; ++i) {
            const int d = ty + i * 16;
            const float4 w4 = *(const float4*)&W[((size_t)n * D_ + d0 + d) * V_ + v0 + tx * 4];
            tile[d][tx * 4 + 0] = f2bf(w4.x);
            tile[d][tx * 4 + 1] = f2bf(w4.y);
            tile[d][tx * 4 + 2] = f2bf(w4.z);
            tile[d][tx * 4 + 3] = f2bf(w4.w);
        }
        __syncthreads();
#pragma unroll
        for (int i = 0; i < 4; ++i) {
            const int v = ty + i * 16;
            ushort4 pk;
            pk.x = tile[tx * 4 + 0][v];
            pk.y = tile[tx * 4 + 1][v];
            pk.z = tile[tx * 4 + 2][v];
            pk.w = tile[tx * 4 + 3][v];
            *reinterpret_cast<ushort4*>(&Wt[((size_t)n * V_ + v0 + v) * D_ + d0 + tx * 4]) = pk;
        }
    } else {
        __shared__ float redS[4], redQ[4];
        const int b = bid;
        const int d0 = t * 4;
        const int lane = t & 63, wid = t >> 6;

        float4 s  = *(const float4*)&ie[(size_t)b * D_ + d0];
        const float4 g4 = *(const float4*)&gamma[d0];
        const float4 be4 = *(const float4*)&beta[d0];

        int fc[N_];
#pragma unroll
        for (int n = 0; n < N_; ++n) fc[n] = feats[b * N_ + n];

#pragma unroll
        for (int n = 0; n < N_; ++n) {
            float ls = s.x + s.y + s.z + s.w;
            float lq = s.x * s.x + s.y * s.y + s.z * s.z + s.w * s.w;
#pragma unroll
            for (int off = 32; off > 0; off >>= 1) {
                ls += __shfl_down(ls, off, 64);
                lq += __shfl_down(lq, off, 64);
            }
            if (lane == 0) { redS[wid] = ls; redQ[wid] = lq; }
            __syncthreads();
            const float tot  = redS[0] + redS[1] + redS[2] + redS[3];
            const float totq = redQ[0] + redQ[1] + redQ[2] + redQ[3];
            __syncthreads();

            const float mu   = tot * (1.0f / D_);
            const float var  = totq * (1.0f / D_) - mu * mu;
            const float rstd = rsqrtf(var + LN_EPS_);

            float h0 = (s.x - mu) * rstd * g4.x + be4.x;
            float h1 = (s.y - mu) * rstd * g4.y + be4.y;
            float h2 = (s.z - mu) * rstd * g4.z + be4.z;
            float h3 = (s.w - mu) * rstd * g4.w + be4.w;
            h0 = 0.5f * h0 * (1.0f + erff(h0 * 0.70710678f));
            h1 = 0.5f * h1 * (1.0f + erff(h1 * 0.70710678f));
            h2 = 0.5f * h2 * (1.0f + erff(h2 * 0.70710678f));
            h3 = 0.5f * h3 * (1.0f + erff(h3 * 0.70710678f));

            ushort4 pk;
            pk.x = f2bf(h0); pk.y = f2bf(h1); pk.z = f2bf(h2); pk.w = f2bf(h3);
            *reinterpret_cast<ushort4*>(&H[((size_t)n * B_ + b) * D_ + d0]) = pk;

            const float4 e = *(const float4*)&emb[((size_t)n * V_ + fc[n]) * (size_t)D_ + d0];
            s.x += e.x; s.y += e.y; s.z += e.z; s.w += e.w;
        }
    }
}

// ---------------------------------------------------------------------------
// gemmd: deep-K persistent GEMM. 256x128 tile, BK=64, 8 waves (2x4).
// Grid = 256 (1 block/CU, single round). Each block loops n=0..7 at fixed
// (mt,vt): 128 continuous K-tiles through one counted-vmcnt pipeline.
// 3 LDS buffers x (A 32KB + B 16KB) = 144KB; depth-2 prefetch, vmcnt(6)/tile.
// Per-n epilogue: stores first, restage, one vmcnt(6) -> stores drain, the
// 6 fresh loads stay in flight (loads are FIFO-older than stores everywhere).
// Swizzle (R2-proven, 0 conflicts): phys 16B slot = logical ^ (row&7),
// inverse pre-applied on the global source.
// ---------------------------------------------------------------------------
#define BUFSZ 49152

#define MF(a, b, c) __builtin_amdgcn_mfma_f32_16x16x32_bf16((a), (b), (c), 0, 0, 0)

#define STAGE6(As, Bs, bb) { \
    __builtin_amdgcn_global_load_lds(GLB((As) + (size_t)(srow      ) * D_ + gsl), LDSP(lds + (bb) +          t * 16), 16, 0, 0); \
    __builtin_amdgcn_global_load_lds(GLB((As) + (size_t)(srow +  64) * D_ + gsl), LDSP(lds + (bb) +  8192 + t * 16), 16, 0, 0); \
    __builtin_amdgcn_global_load_lds(GLB((As) + (size_t)(srow + 128) * D_ + gsl), LDSP(lds + (bb) + 16384 + t * 16), 16, 0, 0); \
    __builtin_amdgcn_global_load_lds(GLB((As) + (size_t)(srow + 192) * D_ + gsl), LDSP(lds + (bb) + 24576 + t * 16), 16, 0, 0); \
    __builtin_amdgcn_global_load_lds(GLB((Bs) + (size_t)(srow      ) * D_ + gsl), LDSP(lds + (bb) + 32768 + t * 16), 16, 0, 0); \
    __builtin_amdgcn_global_load_lds(GLB((Bs) + (size_t)(srow +  64) * D_ + gsl), LDSP(lds + (bb) + 40960 + t * 16), 16, 0, 0); \
}

#define RD_A(i, ks, bb) (*(const bf16x8*)(lds + (bb) + \
    (wr * 128 + (i) * 16 + lrow) * 128 + ((((ks) * 4 + lkq) ^ (lrow & 7)) * 16)))
#define RD_B(j, ks, bb) (*(const bf16x8*)(lds + (bb) + 32768 + \
    (wc * 32 + (j) * 16 + lrow) * 128 + ((((ks) * 4 + lkq) ^ (lrow & 7)) * 16)))

#define MFI(i, Ak0, Ak1) \
    acc[i][0] = MF(Ak0, B00, acc[i][0]); \
    acc[i][0] = MF(Ak1, B01, acc[i][0]); \
    acc[i][1] = MF(Ak0, B10, acc[i][1]); \
    acc[i][1] = MF(Ak1, B11, acc[i][1]);

#define COMPUTE(bb) { \
    bf16x8 B00 = RD_B(0, 0, bb), B01 = RD_B(0, 1, bb), B10 = RD_B(1, 0, bb), B11 = RD_B(1, 1, bb); \
    bf16x8 A00 = RD_A(0, 0, bb), A01 = RD_A(0, 1, bb), A10 = RD_A(1, 0, bb), A11 = RD_A(1, 1, bb); \
    bf16x8 A20 = RD_A(2, 0, bb), A21 = RD_A(2, 1, bb), A30 = RD_A(3, 0, bb), A31 = RD_A(3, 1, bb); \
    __builtin_amdgcn_s_setprio(1); \
    MFI(0, A00, A01) MFI(1, A10, A11) MFI(2, A20, A21) MFI(3, A30, A31) \
    __builtin_amdgcn_s_setprio(0); \
    A00 = RD_A(4, 0, bb); A01 = RD_A(4, 1, bb); A10 = RD_A(5, 0, bb); A11 = RD_A(5, 1, bb); \
    A20 = RD_A(6, 0, bb); A21 = RD_A(6, 1, bb); A30 = RD_A(7, 0, bb); A31 = RD_A(7, 1, bb); \
    __builtin_amdgcn_s_setprio(1); \
    MFI(4, A00, A01) MFI(5, A10, A11) MFI(6, A20, A21) MFI(7, A30, A31) \
    __builtin_amdgcn_s_setprio(0); \
}

// compute tile (gs-2) from buffer bc, stage tile gs into buffer bn
#define TILE_STEP(GS, bc, bn) { \
    const int gs_ = (GS) & 127; \
    const int n2_ = gs_ >> 4; \
    const int k2_ = (gs_ & 15) * 64; \
    const unsigned short* As = H  + ((size_t)n2_ * B_ + (size_t)mt * 256) * D_ + k2_; \
    const unsigned short* Bs = Wt + ((size_t)n2_ * V_ + (size_t)vt * 128) * D_ + k2_; \
    asm volatile("s_waitcnt vmcnt(6)" ::: "memory"); \
    __builtin_amdgcn_s_barrier(); \
    STAGE6(As, Bs, bn); \
    COMPUTE(bc); \
}

#define EPILOG(nn) { \
    _Pragma("unroll") for (int i = 0; i < 8; ++i) { \
        const int row = mt * 256 + wr * 128 + i * 16 + rg; \
        _Pragma("unroll") for (int r = 0; r < 4; ++r) { \
            float* po = out + ((size_t)(row + r) * N_ + (nn)) * V_ + gc0; \
            po[0]  = acc[i][0][r] + bb0[nn]; \
            po[16] = acc[i][1][r] + bb1[nn]; \
        } \
        acc[i][0] = (f32x4){0.f, 0.f, 0.f, 0.f}; \
        acc[i][1] = (f32x4){0.f, 0.f, 0.f, 0.f}; \
    } \
}

// boundary tile: compute tile nn*16+15 from bc; stores; restage into bn; drain stores
#define TILE_BND(nn, bc, bn) { \
    asm volatile("s_waitcnt vmcnt(6)" ::: "memory"); \
    __builtin_amdgcn_s_barrier(); \
    COMPUTE(bc); \
    EPILOG(nn); \
    __builtin_amdgcn_sched_barrier(0); \
    { \
        const int gs_ = ((nn) * 16 + 17) & 127; \
        const int n2_ = gs_ >> 4; \
        const int k2_ = (gs_ & 15) * 64; \
        const unsigned short* As = H  + ((size_t)n2_ * B_ + (size_t)mt * 256) * D_ + k2_; \
        const unsigned short* Bs = Wt + ((size_t)n2_ * V_ + (size_t)vt * 128) * D_ + k2_; \
        STAGE6(As, Bs, bn); \
    } \
    asm volatile("s_waitcnt vmcnt(6)" ::: "memory"); \
}

__global__ __launch_bounds__(512, 2) void gemmd(const unsigned short* __restrict__ H,
                                                const unsigned short* __restrict__ Wt,
                                                const float* __restrict__ bp,
                                                float* __restrict__ out) {
    extern __shared__ char lds[];
    const int bid = blockIdx.x;
    // XCD k (= bid&7) owns vt in [4k, 4k+4) x all mt: per-n working set ~5MB ~ L2
    const int logical = (bid & 7) * 32 + (bid >> 3);
    const int vt = (logical >> 5) * 4 + (logical & 3);  // 0..31
    const int mt = (logical >> 2) & 7;                  // 0..7

    const int t = threadIdx.x;
    const int wid = t >> 6, lane = t & 63;
    const int wr = wid >> 2;   // 0..1  (128-row half)
    const int wc = wid & 3;    // 0..3  (32-col quarter)

    const int srow = t >> 3;                         // 0..63 staging row in 64-row unit
    const int gsl  = ((t & 7) ^ ((t >> 3) & 7)) * 8; // inverse-swizzled source slot (elems)
    const int lrow = lane & 15;
    const int lkq  = lane >> 4;
    const int col  = lane & 15;
    const int rg   = (lane >> 4) * 4;
    const int gc0  = vt * 128 + wc * 32 + col;

    // preload biases for all n (fully drained before the pipeline starts)
    float bb0[8], bb1[8];
#pragma unroll
    for (int n = 0; n < 8; ++n) {
        bb0[n] = bp[(size_t)n * V_ + gc0];
        bb1[n] = bp[(size_t)n * V_ + gc0 + 16];
    }
    asm volatile("s_waitcnt vmcnt(0)" ::: "memory");

    f32x4 acc[8][2] = {};

    // prologue: stage tiles g=0 (buf0) and g=1 (buf1)
    {
        const unsigned short* As = H  + (size_t)mt * 256 * D_;
        const unsigned short* Bs = Wt + (size_t)vt * 128 * D_;
        STAGE6(As, Bs, 0);
        STAGE6(As + 64, Bs + 64, BUFSZ);
    }

#pragma unroll
    for (int n = 0; n < 8; ++n) {
        // buffer phase for this n: tile g = 16n + kk uses buf (n + kk) % 3
        constexpr int P0 = 0, P1 = BUFSZ, P2 = 2 * BUFSZ;
        const int c0 = (n % 3 == 0) ? P0 : (n % 3 == 1) ? P1 : P2;
        const int c1 = (n % 3 == 0) ? P1 : (n % 3 == 1) ? P2 : P0;
        const int c2 = (n % 3 == 0) ? P2 : (n % 3 == 1) ? P0 : P1;
#pragma unroll 1
        for (int kk5 = 0; kk5 < 5; ++kk5) {
            const int g0 = n * 16 + kk5 * 3;
            TILE_STEP(g0 + 2, c0, c2);
            TILE_STEP(g0 + 3, c1, c0);
            TILE_STEP(g0 + 4, c2, c1);
        }
        // tile 15 of this n: buf (n+15)%3 == n%3 == c0, stage target c2
        TILE_BND(n, c0, c2);
    }
}

// ---------------------------------------------------------------------------
extern "C" void kernel_launch(void* const* d_in, const int* in_sizes, int n_in,
                              void* d_out, int out_size, void* d_ws, size_t ws_size,
                              hipStream_t stream) {
    const float* ie  = (const float*)d_in[0];
    const int*   fts = (const int*)d_in[1];
    const float* emb = (const float*)d_in[2];
    const float* W   = (const float*)d_in[3];
    const float* bp  = (const float*)d_in[4];
    const float* gam = (const float*)d_in[5];
    const float* bet = (const float*)d_in[6];
    float* out = (float*)d_out;

    unsigned short* Wt = (unsigned short*)d_ws;                                     // 64 MiB
    unsigned short* H  = (unsigned short*)((char*)d_ws + (size_t)N_ * V_ * D_ * 2); // +32 MiB

    (void)hipFuncSetAttribute(reinterpret_cast<const void*>(gemmd),
                              hipFuncAttributeMaxDynamicSharedMemorySize, 3 * BUFSZ);

    prep<<<dim3(2048 + 8192), dim3(256), 0, stream>>>(ie, fts, emb, gam, bet, W, H, Wt);
    gemmd<<<dim3(256), dim3(512), 3 * BUFSZ, stream>>>(H, Wt, bp, out);
}